// Round 7
// baseline (326.165 us; speedup 1.0000x reference)
//
#include <hip/hip_runtime.h>
#include <math.h>

typedef unsigned int uint;
typedef unsigned short ushort;

#define NROWS 65536
#define KCB   1024
#define DDIM  256
#define MARGIN 0.01f

// d_out layout (floats)
#define OUT_ZQ    0
#define OUT_LOSS  16777216
#define OUT_IDX   16777217
#define OUT_PERP  16842753
#define OUT_USAGE 16842754

typedef __attribute__((ext_vector_type(8)))  short s16x8;
typedef __attribute__((ext_vector_type(16))) float f32x16;

__device__ __forceinline__ ushort bf16rne(float x) {
  uint u = __float_as_uint(x);
  return (ushort)((u + 0x7FFFu + ((u >> 16) & 1u)) >> 16);
}
__device__ __forceinline__ float bf2f(ushort h) {
  return __uint_as_float((uint)h << 16);
}

// ---------------------------------------------------------------------------
// Kernel 1: codebook = normalize(lb @ W.T) * 16 in fp64; emit fp64, fp32,
// and bf16 hi/lo split copies. Round-7 rewrite: wave-per-output-row with
// coalesced float4 W reads (L2-hot) + f64 shfl reduction; no big LDS tile.
// ---------------------------------------------------------------------------
__global__ __launch_bounds__(256) void cb_kernel(const float* __restrict__ lb,
                                                 const float* __restrict__ W,
                                                 double* __restrict__ cb64,
                                                 float* __restrict__ cb32,
                                                 double* __restrict__ c264,
                                                 ushort* __restrict__ ch,
                                                 ushort* __restrict__ cl) {
  const int k    = blockIdx.x;
  const int t    = threadIdx.x;
  const int w    = t >> 6;
  const int lane = t & 63;
  __shared__ float  lb_sh[256];
  __shared__ double vals[256];
  __shared__ double red[256];

  lb_sh[t] = lb[k * 256 + t];
  __syncthreads();

  double lbf[4];
#pragma unroll
  for (int e = 0; e < 4; ++e) lbf[e] = (double)lb_sh[lane * 4 + e];

  // wave w computes output elements [w*64, w*64+64)
  for (int i = 0; i < 64; ++i) {
    const int ig = w * 64 + i;
    float4 wv = *(const float4*)&W[(size_t)ig * 256 + lane * 4];
    double p = lbf[0] * (double)wv.x + lbf[1] * (double)wv.y +
               lbf[2] * (double)wv.z + lbf[3] * (double)wv.w;
#pragma unroll
    for (int off = 32; off > 0; off >>= 1) p += __shfl_xor(p, off);
    if (lane == 0) vals[ig] = p;
  }
  __syncthreads();

  double a = vals[t];
  red[t] = a * a;
  __syncthreads();
  for (int s = 128; s > 0; s >>= 1) {
    if (t < s) red[t] += red[t + s];
    __syncthreads();
  }
  double norm  = sqrt(red[0]);
  double scale = 16.0 / fmax(norm, 1e-12);
  double v     = a * scale;
  cb64[k * 256 + t] = v;
  float cf = (float)v;
  cb32[k * 256 + t] = cf;
  ushort hh = bf16rne(cf);
  ch[k * 256 + t] = hh;
  cl[k * 256 + t] = bf16rne(cf - bf2f(hh));

  __syncthreads();
  red[t] = v * v;
  __syncthreads();
  for (int s = 128; s > 0; s >>= 1) {
    if (t < s) red[t] += red[t + s];
    __syncthreads();
  }
  if (t == 0) c264[k] = red[0];
}

// ---------------------------------------------------------------------------
// Kernel 2: fused MFMA argmax + gather (swapped operands, round-7 schedule).
// D = cb . z^T, one z-row per lane, cb streamed through LDS.
// Round-7 changes vs round 6:
//  (a) conflict-free LDS permutation: slot pi(row,q) = (row&7) + 8q +
//      32*(row>>3)  => 16B-granule = row&7; any 8 consecutive read lanes hit
//      8 distinct granules. Linear gload_lds dest, permuted global source.
//  (b) 3-buffer pipeline, ONE raw s_barrier per step, counted vmcnt(2)
//      (vmcnt(0) only at the last step) -- loads stay in flight across
//      barriers (T3/T4).
//  (c) z split in-kernel from fp32 (zsplit kernel dropped; z rows are
//      block-private so presplit saved no traffic).
// ---------------------------------------------------------------------------
__global__ __launch_bounds__(256, 2) void argmax_mfma(const float* __restrict__ z,
                                                      const ushort* __restrict__ ch,
                                                      const ushort* __restrict__ cl,
                                                      const float* __restrict__ cb32,
                                                      float* __restrict__ out_idx,
                                                      int* __restrict__ idx_int,
                                                      int* __restrict__ flagc,
                                                      int* __restrict__ flagr,
                                                      float* __restrict__ zq,
                                                      double* __restrict__ msep,
                                                      int* __restrict__ counts) {
  const int t     = threadIdx.x;
  const int lane  = t & 63;
  const int w     = t >> 6;
  const int h     = lane >> 5;     // k-slot half
  const int ra    = lane & 31;
  const int mtile = blockIdx.x;

  __shared__ alignas(128) char cbuf[3][8192];  // [buf]: CH pi-tile @0, CL @4096
  __shared__ int    sidx[128];
  __shared__ double partial[4];

  // ---- z fragments: one z-row per lane, split fp32 -> bf16 hi/lo in-reg ----
  s16x8 zh[16], zl[16];
  const int zrow = mtile * 128 + w * 32 + ra;
#pragma unroll
  for (int s = 0; s < 16; ++s) {
    const float* zp = &z[(size_t)zrow * 256 + s * 16 + h * 8];
    float4 f0 = *(const float4*)zp;
    float4 f1 = *(const float4*)(zp + 4);
    float xs[8] = {f0.x, f0.y, f0.z, f0.w, f1.x, f1.y, f1.z, f1.w};
#pragma unroll
    for (int e = 0; e < 8; ++e) {
      ushort hh = bf16rne(xs[e]);
      zh[s][e] = (short)hh;
      zl[s][e] = (short)bf16rne(xs[e] - bf2f(hh));
    }
  }

  // ---- staging: wave w fills slots [w*128, w*128+128) of the 512-slot
  //      (16B each) tile; linear dest, permuted source. step = nt*8 + kt. ----
  auto stage = [&](int buf, int step) {
    const int nt = step >> 3;
    const int kt = step & 7;
#pragma unroll
    for (int j = 0; j < 2; ++j) {
      int slot = w * 128 + j * 64 + lane;
      int tile = slot >> 8;
      int sl   = slot & 255;
      int row  = (sl >> 5) * 8 + (sl & 7);
      int q    = (sl >> 3) & 3;
      const ushort* sb  = tile ? cl : ch;
      const ushort* src = sb + (size_t)(nt * 64 + row) * 256 + kt * 32 + q * 8;
      __builtin_amdgcn_global_load_lds(
          (const __attribute__((address_space(1))) void*)src,
          (__attribute__((address_space(3))) void*)(&cbuf[0][0] + buf * 8192 + (w * 128 + j * 64) * 16),
          16, 0, 0);
    }
  };

  float m1 = -3.0e38f, m2 = -3.0e38f;
  int   i1 = 0;

  stage(0, 0);
  stage(1, 1);

  f32x16 acc0 = 0.0f, acc1 = 0.0f;
  int bread = 0, bstage = 2;

#pragma unroll 1
  for (int nt = 0; nt < 16; ++nt) {
#pragma unroll
    for (int kt = 0; kt < 8; ++kt) {
      const int step = nt * 8 + kt;

      // counted-vmcnt wait for this step's tile, then barrier.
      if (step != 127) asm volatile("s_waitcnt vmcnt(2)" ::: "memory");
      else             asm volatile("s_waitcnt vmcnt(0)" ::: "memory");
      __builtin_amdgcn_s_barrier();
      asm volatile("" ::: "memory");

      // prefetch tile step+2 (stays in flight across the next barrier)
      if (step < 126) stage(bstage, step + 2);

      // compute on buf `bread`
      const char* cb = &cbuf[0][0] + bread * 8192;
#pragma unroll
      for (int ks = 0; ks < 2; ++ks) {
        const int s = ks * 2 + h;
        auto afrag = [&](int tile, int row) -> s16x8 {
          // byte = tile*4096 + pi(row, s)*16
          return *(const s16x8*)(cb + tile * 4096 + (row & 7) * 16 + s * 128 + (row >> 3) * 512);
        };
        s16x8 ah0 = afrag(0, ra);
        s16x8 ah1 = afrag(0, 32 + ra);
        s16x8 al0 = afrag(1, ra);
        s16x8 al1 = afrag(1, 32 + ra);
        const s16x8 bh = zh[kt * 2 + ks];
        const s16x8 bl = zl[kt * 2 + ks];
        acc0 = __builtin_amdgcn_mfma_f32_32x32x16_bf16(ah0, bh, acc0, 0, 0, 0);
        acc1 = __builtin_amdgcn_mfma_f32_32x32x16_bf16(ah1, bh, acc1, 0, 0, 0);
        acc0 = __builtin_amdgcn_mfma_f32_32x32x16_bf16(al0, bh, acc0, 0, 0, 0);
        acc1 = __builtin_amdgcn_mfma_f32_32x32x16_bf16(al1, bh, acc1, 0, 0, 0);
        acc0 = __builtin_amdgcn_mfma_f32_32x32x16_bf16(ah0, bl, acc0, 0, 0, 0);
        acc1 = __builtin_amdgcn_mfma_f32_32x32x16_bf16(ah1, bl, acc1, 0, 0, 0);
      }

      // rotate buffers
      bread  = (bread == 2)  ? 0 : bread + 1;
      bstage = (bstage == 2) ? 0 : bstage + 1;
    }

    // fold this nt's 64 codes into the lane's single (m1, m2, i1) state.
    // D-row (code) = (p&3) + 8*(p>>2) + 4*h (+32 for acc1), col = zrow.
#pragma unroll
    for (int p = 0; p < 16; ++p) {
      const int crow = (p & 3) + 8 * (p >> 2) + 4 * h;
      const int c0   = nt * 64 + crow;
      float v0 = acc0[p];
      if (v0 > m1) { m2 = m1; m1 = v0; i1 = c0; }
      else         { m2 = fmaxf(m2, v0); }
      float v1 = acc1[p];
      if (v1 > m1) { m2 = m1; m1 = v1; i1 = c0 + 32; }
      else         { m2 = fmaxf(m2, v1); }
    }
    acc0 = 0.0f;
    acc1 = 0.0f;
  }

  // ---- single cross-lane merge: lane <-> lane^32 (code halves) ----
  {
    float om1 = __shfl_xor(m1, 32);
    float om2 = __shfl_xor(m2, 32);
    int   oi1 = __shfl_xor(i1, 32);
    if (om1 > m1 || (om1 == m1 && oi1 < i1)) {
      m2 = fmaxf(m1, om2); m1 = om1; i1 = oi1;
    } else {
      m2 = fmaxf(m2, om1);
    }
  }

  if (lane < 32) {
    const int row = mtile * 128 + w * 32 + lane;
    sidx[w * 32 + lane] = i1;
    idx_int[row] = i1;
    out_idx[row] = (float)i1;
    if (m1 - m2 < MARGIN) {
      int pos = atomicAdd(flagc, 1);
      flagr[pos] = row;
    }
  }
  __syncthreads();

  // ---- fused gather: z_q write, mse partial, counts ----
  double msum = 0.0;
  for (int rr = w; rr < 128; rr += 4) {
    const int code = sidx[rr];
    const int grow = mtile * 128 + rr;
    float4 c = *(const float4*)&cb32[(size_t)code * 256 + lane * 4];
    *(float4*)&zq[(size_t)grow * 256 + lane * 4] = c;
    float4 zr = *(const float4*)&z[(size_t)grow * 256 + lane * 4];
    double d;
    d = (double)c.x - (double)zr.x; msum += d * d;
    d = (double)c.y - (double)zr.y; msum += d * d;
    d = (double)c.z - (double)zr.z; msum += d * d;
    d = (double)c.w - (double)zr.w; msum += d * d;
    if (lane == 0) atomicAdd(&counts[code], 1);
  }
#pragma unroll
  for (int off = 32; off > 0; off >>= 1) msum += __shfl_xor(msum, off);
  if (lane == 0) partial[w] = msum;
  __syncthreads();
  if (t == 0) msep[mtile] = partial[0] + partial[1] + partial[2] + partial[3];
}

// ---------------------------------------------------------------------------
// Kernel 3: exact fp64 re-solve of flagged rows; patches idx, z_q, counts,
// and accumulates the mse delta for rows whose index changes.
// ---------------------------------------------------------------------------
__global__ __launch_bounds__(256) void refine_kernel(const float* __restrict__ z,
                                                     const double* __restrict__ cb64,
                                                     const double* __restrict__ c264,
                                                     const float* __restrict__ cb32,
                                                     const int* __restrict__ flagc,
                                                     const int* __restrict__ flagr,
                                                     int* __restrict__ idx_int,
                                                     float* __restrict__ out_idx,
                                                     float* __restrict__ zq,
                                                     int* __restrict__ counts,
                                                     double* __restrict__ msedelta) {
  const int cnt  = *flagc;
  const int t    = threadIdx.x;
  const int w    = t >> 6;
  const int lane = t & 63;
  __shared__ double bs[4];
  __shared__ int    bi[4];
  __shared__ int    shI, shO;
  __shared__ double red[256];

  for (int fi = blockIdx.x; fi < cnt; fi += gridDim.x) {
    const int row = flagr[fi];
    double zr[4];
#pragma unroll
    for (int jj = 0; jj < 4; ++jj)
      zr[jj] = (double)z[row * DDIM + jj * 64 + lane];

    double best = -1e300;
    int bidx = 0;
    for (int k = w * 256; k < w * 256 + 256; ++k) {
      double p = 0.0;
#pragma unroll
      for (int jj = 0; jj < 4; ++jj)
        p += zr[jj] * cb64[k * DDIM + jj * 64 + lane];
#pragma unroll
      for (int off = 32; off > 0; off >>= 1) p += __shfl_xor(p, off);
      double sc = 2.0 * p - c264[k];
      if (sc > best) { best = sc; bidx = k; }   // ascending k: tie -> smaller
    }
    if (lane == 0) { bs[w] = best; bi[w] = bidx; }
    __syncthreads();
    if (t == 0) {
      double B = bs[0]; int I = bi[0];
#pragma unroll
      for (int w2 = 1; w2 < 4; ++w2) {
        if (bs[w2] > B || (bs[w2] == B && bi[w2] < I)) { B = bs[w2]; I = bi[w2]; }
      }
      shO = idx_int[row];
      shI = I;
      if (I != shO) {
        idx_int[row] = I;
        out_idx[row] = (float)I;
        atomicSub(&counts[shO], 1);
        atomicAdd(&counts[I], 1);
      }
    }
    __syncthreads();
    const int I = shI, O = shO;
    if (I != O) {
      float zz = z[row * DDIM + t];
      float cn = cb32[I * DDIM + t];
      float co = cb32[O * DDIM + t];
      zq[(size_t)row * DDIM + t] = cn;
      double dn = (double)cn - (double)zz;
      double dd = (double)co - (double)zz;
      red[t] = dn * dn - dd * dd;
      __syncthreads();
      for (int s = 128; s > 0; s >>= 1) {
        if (t < s) red[t] += red[t + s];
        __syncthreads();
      }
      if (t == 0) atomicAdd(msedelta, red[0]);
    }
    __syncthreads();
  }
}

// ---------------------------------------------------------------------------
// Kernel 4: scalars -- vq_loss, perplexity, codebook_usage.
// ---------------------------------------------------------------------------
__global__ __launch_bounds__(256) void finalize_kernel(const int* __restrict__ counts,
                                                       const double* __restrict__ msep,
                                                       const double* __restrict__ msedelta,
                                                       float* __restrict__ out) {
  const int t = threadIdx.x;
  double ms = 0.0;
#pragma unroll
  for (int i = t; i < 512; i += 256) ms += msep[i];
  if (t == 0) ms += *msedelta;

  double ent = 0.0;
  int used = 0;
#pragma unroll
  for (int i = t; i < KCB; i += 256) {
    int c = counts[i];
    if (c > 0) used++;
    double p = (double)c / (double)NROWS;
    ent += p * log(p + 1e-10);
  }
  __shared__ double se[256];
  __shared__ double sm[256];
  __shared__ int    su[256];
  se[t] = ent; sm[t] = ms; su[t] = used;
  __syncthreads();
  for (int s = 128; s > 0; s >>= 1) {
    if (t < s) { se[t] += se[t + s]; sm[t] += sm[t + s]; su[t] += su[t + s]; }
    __syncthreads();
  }
  if (t == 0) {
    double mse = sm[0] / ((double)NROWS * (double)DDIM);
    out[OUT_LOSS]  = (float)(1.25 * mse);
    out[OUT_PERP]  = (float)exp(-se[0]);
    out[OUT_USAGE] = (float)((double)su[0] / (double)KCB);
  }
}

// ---------------------------------------------------------------------------
extern "C" void kernel_launch(void* const* d_in, const int* in_sizes, int n_in,
                              void* d_out, int out_size, void* d_ws, size_t ws_size,
                              hipStream_t stream) {
  const float* z  = (const float*)d_in[0];   // [65536][256]
  const float* lb = (const float*)d_in[1];   // [1024][256]
  const float* W  = (const float*)d_in[2];   // [256][256]
  float* out = (float*)d_out;

  char* base = (char*)d_ws;
  double* cb64    = (double*)(base + 0x000000);  // 2 MB
  ushort* ch      = (ushort*)(base + 0x200000);  // 512 KB
  ushort* cl      = (ushort*)(base + 0x280000);  // 512 KB
  float*  cb32    = (float*) (base + 0x300000);  // 1 MB
  double* c264    = (double*)(base + 0x400000);  // 8 KB
  int*    idxi    = (int*)   (base + 0x402000);  // 256 KB
  int*    flagr   = (int*)   (base + 0x442000);  // 256 KB
  int*    counts  = (int*)   (base + 0x482000);  // 4 KB   } one zeroed
  int*    flagc   = (int*)   (base + 0x483000);  // 4 B    } contiguous
  double* msedel  = (double*)(base + 0x483008);  // 8 B    } region
  double* msep    = (double*)(base + 0x484000);  // 4 KB (512 doubles)

  hipMemsetAsync(counts, 0, 0x1010, stream);     // counts + flagc + msedel

  cb_kernel<<<KCB, 256, 0, stream>>>(lb, W, cb64, cb32, c264, ch, cl);
  argmax_mfma<<<NROWS / 128, 256, 0, stream>>>(z, ch, cl, cb32,
                                               out + OUT_IDX, idxi, flagc, flagr,
                                               out + OUT_ZQ, msep, counts);
  refine_kernel<<<512, 256, 0, stream>>>(z, cb64, c264, cb32, flagc, flagr,
                                         idxi, out + OUT_IDX, out + OUT_ZQ,
                                         counts, msedel);
  finalize_kernel<<<1, 256, 0, stream>>>(counts, msep, msedel, out);
}

// Round 8
// 236.450 us; speedup vs baseline: 1.3794x; 1.3794x over previous
//
#include <hip/hip_runtime.h>
#include <math.h>

typedef unsigned int uint;
typedef unsigned short ushort;

#define NROWS 65536
#define KCB   1024
#define DDIM  256
#define MARGIN 0.01f

// d_out layout (floats)
#define OUT_ZQ    0
#define OUT_LOSS  16777216
#define OUT_IDX   16777217
#define OUT_PERP  16842753
#define OUT_USAGE 16842754

typedef __attribute__((ext_vector_type(8))) short s16x8;
typedef __attribute__((ext_vector_type(4))) float f32x4;

__device__ __forceinline__ ushort bf16rne(float x) {
  uint u = __float_as_uint(x);
  return (ushort)((u + 0x7FFFu + ((u >> 16) & 1u)) >> 16);
}
__device__ __forceinline__ float bf2f(ushort h) {
  return __uint_as_float((uint)h << 16);
}

// ---------------------------------------------------------------------------
// Kernel 1: codebook = normalize(lb @ W.T) * 16 in fp64 (LDS-staged W, the
// round-6 proven version); emits transposed fp64 (cb64T[j][k] for refine),
// fp32, and bf16 hi/lo split copies.
// ---------------------------------------------------------------------------
__global__ __launch_bounds__(256) void cb_kernel(const float* __restrict__ lb,
                                                 const float* __restrict__ W,
                                                 double* __restrict__ cb64T,
                                                 float* __restrict__ cb32,
                                                 double* __restrict__ c264,
                                                 ushort* __restrict__ ch,
                                                 ushort* __restrict__ cl) {
  const int k = blockIdx.x;
  const int t = threadIdx.x;
  __shared__ float lb_sh[256];
  __shared__ float W_sh[256 * 66];
  __shared__ double red[256];

  lb_sh[t] = lb[k * 256 + t];

  double acc = 0.0;
  for (int jt = 0; jt < 4; ++jt) {
    __syncthreads();
#pragma unroll
    for (int i = 0; i < 16; ++i) {
      int qid = t + 256 * i;
      int row = qid >> 4;
      int q   = qid & 15;
      float4 v = *(const float4*)&W[row * 256 + jt * 64 + q * 4];
      float* dst = &W_sh[row * 66 + q * 4];
      dst[0] = v.x; dst[1] = v.y; dst[2] = v.z; dst[3] = v.w;
    }
    __syncthreads();
#pragma unroll
    for (int jj = 0; jj < 64; ++jj) {
      acc += (double)lb_sh[jt * 64 + jj] * (double)W_sh[t * 66 + jj];
    }
  }

  red[t] = acc * acc;
  __syncthreads();
  for (int s = 128; s > 0; s >>= 1) {
    if (t < s) red[t] += red[t + s];
    __syncthreads();
  }
  double norm  = sqrt(red[0]);
  double scale = 16.0 / fmax(norm, 1e-12);
  double v     = acc * scale;
  cb64T[(size_t)t * 1024 + k] = v;        // transposed for refine
  float cf = (float)v;
  cb32[k * 256 + t] = cf;
  ushort hh = bf16rne(cf);
  ch[k * 256 + t] = hh;
  cl[k * 256 + t] = bf16rne(cf - bf2f(hh));

  __syncthreads();
  red[t] = v * v;
  __syncthreads();
  for (int s = 128; s > 0; s >>= 1) {
    if (t < s) red[t] += red[t + s];
    __syncthreads();
  }
  if (t == 0) c264[k] = red[0];
}

// ---------------------------------------------------------------------------
// Kernel 2: fused MFMA argmax + gather, 16x16x32 shape (round-8).
// D = cb . z^T, one z-row per lane pair-of-16 (ra=lane&15, q4=lane>>4 is the
// K-quarter). Block = 64 z-rows (4 waves x 16) x all 1024 codes.
// - z frags in registers: 8 chunks x (hi+lo) = 64 VGPR (half of 32x32 shape).
// - grid 1024 = 4 blocks/CU; launch_bounds(256,4) targets 16 waves/CU.
// - LDS tile per step: 64 codes x 32 k x (hi,lo) = 8 KB, K-MAJOR layout
//   (byte = hl*4096 + q*1024 + row*16): read granule = ra%8 -> consecutive
//   lanes hit consecutive granules, conflict-free; linear gload_lds dest.
// - 2-phase double-buffer schedule (round-6 proven): stage(next) -> MFMA ->
//   __syncthreads.
// ---------------------------------------------------------------------------
__global__ __launch_bounds__(256, 4) void argmax_mfma(const float* __restrict__ z,
                                                      const ushort* __restrict__ ch,
                                                      const ushort* __restrict__ cl,
                                                      const float* __restrict__ cb32,
                                                      float* __restrict__ out_idx,
                                                      int* __restrict__ idx_int,
                                                      int* __restrict__ flagc,
                                                      int* __restrict__ flagr,
                                                      float* __restrict__ zq,
                                                      double* __restrict__ msep,
                                                      int* __restrict__ counts) {
  const int t     = threadIdx.x;
  const int lane  = t & 63;
  const int w     = t >> 6;
  const int ra    = lane & 15;     // z-row within wave / code-row within group
  const int q4    = lane >> 4;     // K-quarter (8 bf16 each)
  const int mtile = blockIdx.x;

  __shared__ alignas(128) char cbuf[2][8192];
  __shared__ int    sidx[64];
  __shared__ double partial[4];

  // ---- z fragments: one z-row per lane, fp32 -> bf16 hi/lo in-register ----
  s16x8 zh[8], zl[8];
  const int zrow = mtile * 64 + w * 16 + ra;
#pragma unroll
  for (int c = 0; c < 8; ++c) {
    const float* zp = &z[(size_t)zrow * 256 + c * 32 + q4 * 8];
    float4 f0 = *(const float4*)zp;
    float4 f1 = *(const float4*)(zp + 4);
    float xs[8] = {f0.x, f0.y, f0.z, f0.w, f1.x, f1.y, f1.z, f1.w};
#pragma unroll
    for (int e = 0; e < 8; ++e) {
      ushort hh = bf16rne(xs[e]);
      zh[c][e] = (short)hh;
      zl[c][e] = (short)bf16rne(xs[e] - bf2f(hh));
    }
  }

  // ---- staging: 512 slots of 16B; slot s: hl=s>>8, q=(s>>6)&3, row=s&63.
  //      Linear LDS dest (wave-uniform base), per-lane global source. ----
  auto stage = [&](int buf, int nt, int kt) {
#pragma unroll
    for (int j = 0; j < 2; ++j) {
      int s   = w * 128 + j * 64 + lane;
      int hl  = s >> 8;
      int q   = (s >> 6) & 3;
      int row = s & 63;
      const ushort* sb  = hl ? cl : ch;
      const ushort* src = sb + (size_t)(nt * 64 + row) * 256 + kt * 32 + q * 8;
      __builtin_amdgcn_global_load_lds(
          (const __attribute__((address_space(1))) void*)src,
          (__attribute__((address_space(3))) void*)(&cbuf[buf][0] + (w * 128 + j * 64) * 16),
          16, 0, 0);
    }
  };

  float m1 = -3.0e38f, m2 = -3.0e38f;
  int   i1 = 0;

  stage(0, 0, 0);
  __syncthreads();

#pragma unroll 1
  for (int nt = 0; nt < 16; ++nt) {
    f32x4 acc[4] = {f32x4(0.0f), f32x4(0.0f), f32x4(0.0f), f32x4(0.0f)};
#pragma unroll
    for (int kt = 0; kt < 8; ++kt) {
      const int cur = kt & 1;
      if (kt < 7)       stage(cur ^ 1, nt, kt + 1);
      else if (nt < 15) stage(cur ^ 1, nt + 1, 0);

      const char* cbb = &cbuf[cur][0];
      const s16x8 bh = zh[kt];
      const s16x8 bl = zl[kt];
#pragma unroll
      for (int cg = 0; cg < 4; ++cg) {
        s16x8 ahi = *(const s16x8*)(cbb + q4 * 1024 + (cg * 16 + ra) * 16);
        s16x8 alo = *(const s16x8*)(cbb + 4096 + q4 * 1024 + (cg * 16 + ra) * 16);
        acc[cg] = __builtin_amdgcn_mfma_f32_16x16x32_bf16(ahi, bh, acc[cg], 0, 0, 0);
        acc[cg] = __builtin_amdgcn_mfma_f32_16x16x32_bf16(alo, bh, acc[cg], 0, 0, 0);
        acc[cg] = __builtin_amdgcn_mfma_f32_16x16x32_bf16(ahi, bl, acc[cg], 0, 0, 0);
      }
      __syncthreads();
    }

    // fold this nt's 64 codes into the lane's (m1, m2, i1).
    // D layout (m89/m91): col = lane&15 = zrow; code-row = q4*4 + j.
#pragma unroll
    for (int cg = 0; cg < 4; ++cg) {
#pragma unroll
      for (int j = 0; j < 4; ++j) {
        const int code = nt * 64 + cg * 16 + q4 * 4 + j;
        float v = acc[cg][j];
        if (v > m1) { m2 = m1; m1 = v; i1 = code; }
        else        { m2 = fmaxf(m2, v); }
      }
    }
  }

  // ---- cross-lane merge across the 4 K-quarter copies of each z-row ----
#pragma unroll
  for (int off = 16; off <= 32; off <<= 1) {
    float om1 = __shfl_xor(m1, off);
    float om2 = __shfl_xor(m2, off);
    int   oi1 = __shfl_xor(i1, off);
    if (om1 > m1 || (om1 == m1 && oi1 < i1)) {
      m2 = fmaxf(m1, om2); m1 = om1; i1 = oi1;
    } else {
      m2 = fmaxf(m2, om1);
    }
  }

  if (lane < 16) {
    const int row = mtile * 64 + w * 16 + lane;
    sidx[w * 16 + lane] = i1;
    idx_int[row] = i1;
    out_idx[row] = (float)i1;
    if (m1 - m2 < MARGIN) {
      int pos = atomicAdd(flagc, 1);
      flagr[pos] = row;
    }
  }
  __syncthreads();

  // ---- fused gather: z_q write, mse partial, counts ----
  double msum = 0.0;
  for (int rr = w; rr < 64; rr += 4) {
    const int code = sidx[rr];
    const int grow = mtile * 64 + rr;
    float4 c = *(const float4*)&cb32[(size_t)code * 256 + lane * 4];
    *(float4*)&zq[(size_t)grow * 256 + lane * 4] = c;
    float4 zr = *(const float4*)&z[(size_t)grow * 256 + lane * 4];
    double d;
    d = (double)c.x - (double)zr.x; msum += d * d;
    d = (double)c.y - (double)zr.y; msum += d * d;
    d = (double)c.z - (double)zr.z; msum += d * d;
    d = (double)c.w - (double)zr.w; msum += d * d;
    if (lane == 0) atomicAdd(&counts[code], 1);
  }
#pragma unroll
  for (int off = 32; off > 0; off >>= 1) msum += __shfl_xor(msum, off);
  if (lane == 0) partial[w] = msum;
  __syncthreads();
  if (t == 0) msep[mtile] = partial[0] + partial[1] + partial[2] + partial[3];
}

// ---------------------------------------------------------------------------
// Kernel 3: exact fp64 re-solve of flagged rows (round-8 rewrite): thread t
// owns codes {t, t+256, t+512, t+768}; z-row broadcast from LDS; cb64T reads
// are fully coalesced; no per-k cross-lane reduction. Patches idx, z_q,
// counts, and mse delta for rows whose index changes.
// ---------------------------------------------------------------------------
__global__ __launch_bounds__(256) void refine_kernel(const float* __restrict__ z,
                                                     const double* __restrict__ cb64T,
                                                     const double* __restrict__ c264,
                                                     const float* __restrict__ cb32,
                                                     const int* __restrict__ flagc,
                                                     const int* __restrict__ flagr,
                                                     int* __restrict__ idx_int,
                                                     float* __restrict__ out_idx,
                                                     float* __restrict__ zq,
                                                     int* __restrict__ counts,
                                                     double* __restrict__ msedelta) {
  const int cnt = *flagc;
  const int t   = threadIdx.x;
  __shared__ double z_sh[256];
  __shared__ double rs[256];
  __shared__ int    ri[256];
  __shared__ int    shI, shO;
  __shared__ double red[256];

  for (int fi = blockIdx.x; fi < cnt; fi += gridDim.x) {
    const int row = flagr[fi];
    __syncthreads();
    z_sh[t] = (double)z[(size_t)row * DDIM + t];
    __syncthreads();

    double a0 = 0.0, a1 = 0.0, a2 = 0.0, a3 = 0.0;
    for (int j = 0; j < 256; ++j) {
      double zj = z_sh[j];
      const double* cp = &cb64T[(size_t)j * 1024 + t];
      a0 += zj * cp[0];
      a1 += zj * cp[256];
      a2 += zj * cp[512];
      a3 += zj * cp[768];
    }
    double b  = 2.0 * a0 - c264[t];       int bi_ = t;
    double s1 = 2.0 * a1 - c264[t + 256]; if (s1 > b) { b = s1; bi_ = t + 256; }
    double s2 = 2.0 * a2 - c264[t + 512]; if (s2 > b) { b = s2; bi_ = t + 512; }
    double s3 = 2.0 * a3 - c264[t + 768]; if (s3 > b) { b = s3; bi_ = t + 768; }
    rs[t] = b; ri[t] = bi_;
    __syncthreads();
    for (int s = 128; s > 0; s >>= 1) {
      if (t < s) {
        if (rs[t + s] > rs[t] || (rs[t + s] == rs[t] && ri[t + s] < ri[t])) {
          rs[t] = rs[t + s]; ri[t] = ri[t + s];
        }
      }
      __syncthreads();
    }
    if (t == 0) {
      int I = ri[0];
      shO = idx_int[row];
      shI = I;
      if (I != shO) {
        idx_int[row] = I;
        out_idx[row] = (float)I;
        atomicSub(&counts[shO], 1);
        atomicAdd(&counts[I], 1);
      }
    }
    __syncthreads();
    const int I = shI, O = shO;
    if (I != O) {
      float zz = z[(size_t)row * DDIM + t];
      float cn = cb32[(size_t)I * DDIM + t];
      float co = cb32[(size_t)O * DDIM + t];
      zq[(size_t)row * DDIM + t] = cn;
      double dn = (double)cn - (double)zz;
      double dd = (double)co - (double)zz;
      red[t] = dn * dn - dd * dd;
      __syncthreads();
      for (int s = 128; s > 0; s >>= 1) {
        if (t < s) red[t] += red[t + s];
        __syncthreads();
      }
      if (t == 0) atomicAdd(msedelta, red[0]);
    }
    __syncthreads();
  }
}

// ---------------------------------------------------------------------------
// Kernel 4: scalars -- vq_loss, perplexity, codebook_usage.
// ---------------------------------------------------------------------------
__global__ __launch_bounds__(256) void finalize_kernel(const int* __restrict__ counts,
                                                       const double* __restrict__ msep,
                                                       const double* __restrict__ msedelta,
                                                       float* __restrict__ out) {
  const int t = threadIdx.x;
  double ms = 0.0;
#pragma unroll
  for (int i = t; i < 1024; i += 256) ms += msep[i];
  if (t == 0) ms += *msedelta;

  double ent = 0.0;
  int used = 0;
#pragma unroll
  for (int i = t; i < KCB; i += 256) {
    int c = counts[i];
    if (c > 0) used++;
    double p = (double)c / (double)NROWS;
    ent += p * log(p + 1e-10);
  }
  __shared__ double se[256];
  __shared__ double sm[256];
  __shared__ int    su[256];
  se[t] = ent; sm[t] = ms; su[t] = used;
  __syncthreads();
  for (int s = 128; s > 0; s >>= 1) {
    if (t < s) { se[t] += se[t + s]; sm[t] += sm[t + s]; su[t] += su[t + s]; }
    __syncthreads();
  }
  if (t == 0) {
    double mse = sm[0] / ((double)NROWS * (double)DDIM);
    out[OUT_LOSS]  = (float)(1.25 * mse);
    out[OUT_PERP]  = (float)exp(-se[0]);
    out[OUT_USAGE] = (float)((double)su[0] / (double)KCB);
  }
}

// ---------------------------------------------------------------------------
extern "C" void kernel_launch(void* const* d_in, const int* in_sizes, int n_in,
                              void* d_out, int out_size, void* d_ws, size_t ws_size,
                              hipStream_t stream) {
  const float* z  = (const float*)d_in[0];   // [65536][256]
  const float* lb = (const float*)d_in[1];   // [1024][256]
  const float* W  = (const float*)d_in[2];   // [256][256]
  float* out = (float*)d_out;

  char* base = (char*)d_ws;
  double* cb64T   = (double*)(base + 0x000000);  // 2 MB (transposed [j][k])
  ushort* ch      = (ushort*)(base + 0x200000);  // 512 KB
  ushort* cl      = (ushort*)(base + 0x280000);  // 512 KB
  float*  cb32    = (float*) (base + 0x300000);  // 1 MB
  double* c264    = (double*)(base + 0x400000);  // 8 KB
  int*    idxi    = (int*)   (base + 0x402000);  // 256 KB
  int*    flagr   = (int*)   (base + 0x442000);  // 256 KB
  int*    counts  = (int*)   (base + 0x482000);  // 4 KB   } one zeroed
  int*    flagc   = (int*)   (base + 0x483000);  // 4 B    } contiguous
  double* msedel  = (double*)(base + 0x483008);  // 8 B    } region
  double* msep    = (double*)(base + 0x484000);  // 8 KB (1024 doubles)

  hipMemsetAsync(counts, 0, 0x1010, stream);     // counts + flagc + msedel

  cb_kernel<<<KCB, 256, 0, stream>>>(lb, W, cb64T, cb32, c264, ch, cl);
  argmax_mfma<<<NROWS / 64, 256, 0, stream>>>(z, ch, cl, cb32,
                                              out + OUT_IDX, idxi, flagc, flagr,
                                              out + OUT_ZQ, msep, counts);
  refine_kernel<<<512, 256, 0, stream>>>(z, cb64T, c264, cb32, flagc, flagr,
                                         idxi, out + OUT_IDX, out + OUT_ZQ,
                                         counts, msedel);
  finalize_kernel<<<1, 256, 0, stream>>>(counts, msep, msedel, out);
}